// Round 12
// baseline (2316.040 us; speedup 1.0000x reference)
//
#include <hip/hip_runtime.h>
#include <hip/hip_bf16.h>
#include <stdint.h>

namespace {

constexpr int Tn = 512, In = 256, Hn = 256, Kn = 512;

typedef __attribute__((ext_vector_type(8))) short bf16x8;
typedef __attribute__((ext_vector_type(4))) float f32x4;
typedef __attribute__((ext_vector_type(4))) unsigned int u32x4;

__device__ __forceinline__ float sigmoidf_(float x) { return 1.f / (1.f + __expf(-x)); }
__device__ __forceinline__ float tanhf_(float x)    { return 2.f / (1.f + __expf(-2.f * x)) - 1.f; }

__device__ __forceinline__ int swz(int c) { return c ^ ((c >> 4) & 15); }
__device__ __forceinline__ int swz16(int c) { return c ^ (((c >> 3) & 3) << 1); }

// LDS-only barrier (R11-proven): no vmcnt drain on the critical path
__device__ __forceinline__ void bar_lds() {
    asm volatile("s_waitcnt lgkmcnt(0)\n\ts_barrier" ::: "memory");
}

// ---- scoped global ops ----
__device__ __forceinline__ void st16_llc(void* p, bf16x8 v) {
    asm volatile("global_store_dwordx4 %0, %1, off sc1" :: "v"(p), "v"(v) : "memory");
}
__device__ __forceinline__ bf16x8 ld16_llc(const void* p) {
    bf16x8 r;
    asm volatile("global_load_dwordx4 %0, %1, off sc1" : "=v"(r) : "v"(p) : "memory");
    return r;
}
__device__ __forceinline__ u32x4 ldflags_llc(const void* p) {
    u32x4 r;
    asm volatile("global_load_dwordx4 %0, %1, off sc1\n\ts_waitcnt vmcnt(0)"
                 : "=v"(r) : "v"(p) : "memory");
    return r;
}
__device__ __forceinline__ void stdw_llc(void* p, uint32_t v) {
    asm volatile("global_store_dword %0, %1, off sc1" :: "v"(p), "v"(v) : "memory");
}
__device__ __forceinline__ uint32_t lddw_llc(const void* p) {
    uint32_t r;
    asm volatile("global_load_dword %0, %1, off sc1\n\ts_waitcnt vmcnt(0)"
                 : "=v"(r) : "v"(p) : "memory");
    return r;
}
// sc0 = L2-scope (same-XCD fast path)
__device__ __forceinline__ void stdw_l2(void* p, uint32_t v) {
    asm volatile("global_store_dword %0, %1, off sc0" :: "v"(p), "v"(v) : "memory");
}
__device__ __forceinline__ u32x4 ld16u_s(const void* p, bool llc) {
    u32x4 r;
    if (llc) asm volatile("global_load_dwordx4 %0, %1, off sc1" : "=v"(r) : "v"(p) : "memory");
    else     asm volatile("global_load_dwordx4 %0, %1, off sc0" : "=v"(r) : "v"(p) : "memory");
    return r;
}

// tag check: 8 dwords, hi-u16 must all equal want (wt = want<<16)
__device__ __forceinline__ bool tags8(u32x4 a, u32x4 b, uint32_t wt) {
    uint32_t d = (a.x ^ wt) | (a.y ^ wt) | (a.z ^ wt) | (a.w ^ wt)
               | (b.x ^ wt) | (b.y ^ wt) | (b.z ^ wt) | (b.w ^ wt);
    return (d & 0xFFFF0000u) == 0u;
}
__device__ __forceinline__ bf16x8 pack8(u32x4 a, u32x4 b) {
    union { uint32_t u[4]; bf16x8 v; } r;
    r.u[0] = (a.x & 0xFFFFu) | (a.y << 16);
    r.u[1] = (a.z & 0xFFFFu) | (a.w << 16);
    r.u[2] = (b.x & 0xFFFFu) | (b.y << 16);
    r.u[3] = (b.z & 0xFFFFu) | (b.w << 16);
    return r.v;
}

// ===================== TIER 1: XCD-verified clustering ======================
// 256 WGs launched; WG0 gathers per-WG XCC_ID and forms 16 clusters x 4 members
// FROM A SINGLE XCD EACH; 192 WGs exit. Surviving slot (cl,j): cluster cl owns
// batch [16cl,+16), member j owns units [64j,+64). Protocol = R11 tag-in-data,
// exports sc0 (same-XCD L2), polls mixed sc0/sc1 (sniff catches any lazy world).

__global__ void pack_w_tag(const float* __restrict__ W, __hip_bfloat16* __restrict__ Wpf,
                           unsigned long long* __restrict__ hz, uint32_t* __restrict__ tab) {
    int idx  = blockIdx.x * 256 + threadIdx.x;   // 65536 total
    int lane = idx & 63;
    int kb   = (idx >> 6) & 15;
    int nt2  = idx >> 10;
    int g = nt2 & 3, wu = (nt2 >> 2) & 3, jj = nt2 >> 4;
    int row = g * 256 + jj * 64 + wu * 16 + (lane & 15);
    int k0  = kb * 32 + (lane >> 4) * 8;
    const float* src = W + (size_t)row * Kn + k0;
    union { __hip_bfloat16 h[8]; bf16x8 v; } u;
#pragma unroll
    for (int e = 0; e < 8; ++e) u.h[e] = __float2bfloat16(src[e]);
    *(bf16x8*)(Wpf + (size_t)idx * 8) = u.v;
    // zero tagged hbuf (512KB) every launch (stale tags across graph replays)
    hz[idx] = 0ULL;
    // zero assignment tables (xcdtab[256] + asgn[256], live in d_out scratch)
    if (blockIdx.x == 0 && threadIdx.x < 256) {
        tab[threadIdx.x] = 0u;
        tab[256 + threadIdx.x] = 0u;
    }
}

__global__ __launch_bounds__(512, 2) void lstm_xcd(
    const float* __restrict__ X, const float* __restrict__ bias,
    const __hip_bfloat16* __restrict__ Wpf, char* __restrict__ hbuf,
    uint32_t* __restrict__ tab, float* __restrict__ out)
{
    __shared__ bf16x8 AfrX[2][512];    // 16 KB dbuf x frags (also leader scratch)
    __shared__ bf16x8 AfrH[512];       // 8 KB h frags
    __shared__ f32x4 Red[4][4][64];    // 16 KB x-GEMM partials
    __shared__ uint32_t roleSh;

    const int tid = threadIdx.x, lane = tid & 63, w8 = tid >> 6;
    const int wu = w8 & 3, ks = w8 >> 2;
    const int l15 = lane & 15, lk = lane >> 4;
    const int wg = blockIdx.x;

    uint32_t* xcdtab = tab;
    uint32_t* asgn   = tab + 256;

    // ---- publish own XCD id (verified mechanism: learn_hip m09) ----
    uint32_t xcc;
    asm volatile("s_getreg_b32 %0, hwreg(HW_REG_XCC_ID)" : "=s"(xcc));
    if (tid == 0) {
        uint32_t v = (xcc & 7) + 1;
        asm volatile("global_store_dword %0, %1, off sc1\n\ts_waitcnt vmcnt(0)"
                     :: "v"(xcdtab + wg), "v"(v) : "memory");
    }

    // ---- leader: gather ids, form same-XCD clusters, broadcast roles ----
    if (wg == 0) {
        uint32_t* xtabL = (uint32_t*)&AfrX[0][0];
        uint32_t* asgnL = xtabL + 256;
        if (tid < 256) {
            uint32_t v = 0;
            for (uint32_t g2 = 0; g2 < (1u << 16); ++g2) {
                v = lddw_llc(xcdtab + tid);
                if (v != 0) break;
            }
            xtabL[tid] = v;
            asgnL[tid] = 1u;            // default: EXIT
        }
        __syncthreads();
        if (tid == 0) {
            int cnt[8] = {0, 0, 0, 0, 0, 0, 0, 0};
            int pend[8][4];
            int ncl = 0;
            for (int i = 0; i < 256 && ncl < 16; ++i) {
                const int x = (int)((xtabL[i] - 1u) & 7u);
                pend[x][cnt[x] & 3] = i;
                cnt[x]++;
                if ((cnt[x] & 3) == 0) {        // 4 same-XCD WGs -> one cluster
                    for (int m = 0; m < 4; ++m)
                        asgnL[pend[x][m]] = 2u + (uint32_t)(ncl * 4 + m);
                    ncl++;
                }
            }
        }
        __syncthreads();
        if (tid < 256)
            asm volatile("global_store_dword %0, %1, off sc1"
                         :: "v"(asgn + tid), "v"(asgnL[tid]) : "memory");
        asm volatile("s_waitcnt vmcnt(0)" ::: "memory");
    }

    // ---- fetch own role ----
    if (tid == 0) {
        uint32_t v = 0;
        for (uint32_t g2 = 0; g2 < (1u << 20); ++g2) {
            v = lddw_llc(asgn + wg);
            if (v != 0) break;
        }
        roleSh = v;
    }
    __syncthreads();
    const uint32_t role = roleSh;
    if (role < 2u) return;             // EXIT
    const int slot = (int)(role - 2u);
    const int cl = slot >> 2, j = slot & 3;
    __syncthreads();                   // leader LDS scratch fully retired

    // ---- resident weights: 32 frags / lane (ks picks K-half) ----
    bf16x8 wf[4][8];
#pragma unroll
    for (int g = 0; g < 4; ++g)
#pragma unroll
        for (int i = 0; i < 8; ++i) {
            const int nt2 = (j * 4 + wu) * 4 + g, kb = ks * 8 + i;
            wf[g][i] = *(const bf16x8*)(Wpf + ((size_t)(nt2 * 16 + kb) * 64 + lane) * 8);
        }
    float bg[4];
#pragma unroll
    for (int g = 0; g < 4; ++g) bg[g] = bias[g * 256 + j * 64 + wu * 16 + l15];

    float c4[4] = {0.f, 0.f, 0.f, 0.f};

    {
        const bf16x8 z = {};
        AfrH[tid] = z;
    }

    // ---- prologue: stage x(0); prefetch x(1) ----
    const int b = wu * 4 + lk;
    const float* xbase = X + (size_t)(cl * 16 + b) * Tn * In;
    float4 xp[4];
    if (ks == 0) {
#pragma unroll
        for (int cc = 0; cc < 2; ++cc) {
            const int o8 = l15 + cc * 16;
            const float4 v0 = *(const float4*)(xbase + o8 * 8);
            const float4 v1 = *(const float4*)(xbase + o8 * 8 + 4);
            union { __hip_bfloat16 h[8]; bf16x8 v; } u;
            u.h[0] = __float2bfloat16(v0.x); u.h[1] = __float2bfloat16(v0.y);
            u.h[2] = __float2bfloat16(v0.z); u.h[3] = __float2bfloat16(v0.w);
            u.h[4] = __float2bfloat16(v1.x); u.h[5] = __float2bfloat16(v1.y);
            u.h[6] = __float2bfloat16(v1.z); u.h[7] = __float2bfloat16(v1.w);
            AfrX[0][swz(b + 16 * o8)] = u.v;
        }
#pragma unroll
        for (int cc = 0; cc < 2; ++cc) {
            const int o8 = l15 + cc * 16;
            xp[cc * 2]     = *(const float4*)(xbase + In + o8 * 8);
            xp[cc * 2 + 1] = *(const float4*)(xbase + In + o8 * 8 + 4);
        }
    }
    __syncthreads();

#pragma unroll 1
    for (int t = 0; t < Tn; ++t) {
        if (ks == 0) {
            // ---- x-GEMM(t) -> Red; stage x(t+1) (off critical path) ----
            f32x4 acc[4] = {};
            bf16x8 af[8];
#pragma unroll
            for (int i = 0; i < 8; ++i)
                af[i] = AfrX[t & 1][swz(i * 64 + lane)];
#pragma unroll
            for (int i = 0; i < 8; ++i)
#pragma unroll
                for (int g = 0; g < 4; ++g)
                    acc[g] = __builtin_amdgcn_mfma_f32_16x16x32_bf16(af[i], wf[g][i], acc[g], 0, 0, 0);
#pragma unroll
            for (int g = 0; g < 4; ++g) Red[wu][g][lane] = acc[g];
            if (t + 1 < Tn) {
#pragma unroll
                for (int cc = 0; cc < 2; ++cc) {
                    const int o8 = l15 + cc * 16;
                    union { __hip_bfloat16 h[8]; bf16x8 v; } u;
                    u.h[0] = __float2bfloat16(xp[cc * 2].x); u.h[1] = __float2bfloat16(xp[cc * 2].y);
                    u.h[2] = __float2bfloat16(xp[cc * 2].z); u.h[3] = __float2bfloat16(xp[cc * 2].w);
                    u.h[4] = __float2bfloat16(xp[cc * 2 + 1].x); u.h[5] = __float2bfloat16(xp[cc * 2 + 1].y);
                    u.h[6] = __float2bfloat16(xp[cc * 2 + 1].z); u.h[7] = __float2bfloat16(xp[cc * 2 + 1].w);
                    AfrX[(t + 1) & 1][swz(b + 16 * o8)] = u.v;
                }
            }
        } else if (t > 0 && wu != j) {
            // ---- import mate wu's h(t-1): mixed-scope tagged poll ----
            const char* ib = hbuf + (size_t)(((cl * 4 + wu) * 2 + (t & 1)) * 4096)
                           + (lane & 15) * 256 + (lane >> 4) * 32;
            const uint32_t wt = ((uint32_t)t) << 16;
            u32x4 A0 = {}, A1 = {}, B0 = {}, B1 = {};
            bool f0 = false, f1 = false;
            int g2 = 0;
            for (;;) {
                const bool llc = ((g2 & 15) >= 12);   // sc1 sniff 4/16 iters
                if (!f0) { A0 = ld16u_s(ib, llc);       A1 = ld16u_s(ib + 16, llc); }
                if (!f1) { B0 = ld16u_s(ib + 128, llc); B1 = ld16u_s(ib + 144, llc); }
                asm volatile("s_waitcnt vmcnt(0)" ::: "memory");
                f0 = f0 || tags8(A0, A1, wt);
                f1 = f1 || tags8(B0, B1, wt);
                if (__all(f0 && f1) || ++g2 >= 4096) break;
            }
            __builtin_amdgcn_sched_barrier(0);
            AfrH[swz(wu * 128 + lane)]      = pack8(A0, A1);
            AfrH[swz(wu * 128 + 64 + lane)] = pack8(B0, B1);
        }
        bar_lds();   // B2: AfrH(t-1) complete, Red(t) complete, AfrX(t+1) staged

        uint16_t hb[4];
        if (ks == 0) {
            if (t + 2 < Tn) {
                const float* xs = xbase + (size_t)(t + 2) * In;
#pragma unroll
                for (int cc = 0; cc < 2; ++cc) {
                    const int o8 = l15 + cc * 16;
                    xp[cc * 2]     = *(const float4*)(xs + o8 * 8);
                    xp[cc * 2 + 1] = *(const float4*)(xs + o8 * 8 + 4);
                }
            }
        } else {
            // ---- h-GEMM + reduce + gates + export (single wave, R11-proven) ----
            f32x4 acc[4] = {};
            bf16x8 af[8];
#pragma unroll
            for (int i = 0; i < 8; ++i)
                af[i] = AfrH[swz(i * 64 + lane)];
#pragma unroll
            for (int i = 0; i < 8; ++i)
#pragma unroll
                for (int g = 0; g < 4; ++g)
                    acc[g] = __builtin_amdgcn_mfma_f32_16x16x32_bf16(af[i], wf[g][i], acc[g], 0, 0, 0);
#pragma unroll
            for (int g = 0; g < 4; ++g) acc[g] += Red[wu][g][lane];
#pragma unroll
            for (int r = 0; r < 4; ++r) {
                const float pi = acc[0][r] + bg[0];
                const float pj = acc[1][r] + bg[1];
                const float pf = acc[2][r] + bg[2];
                const float po = acc[3][r] + bg[3];
                const float ai = sigmoidf_(pi);
                const float aj = tanhf_(pj);
                const float afv = sigmoidf_(pf);
                const float ao = sigmoidf_(po);
                const float cn = ai * aj + c4[r] * afv;
                c4[r] = cn;
                const float hn = ao * tanhf_(cn);
                if (t < Tn - 1) {
                    union { __hip_bfloat16 bh; uint16_t u; } cv;
                    cv.bh = __float2bfloat16(hn);
                    hb[r] = cv.u;
                } else {
                    out[(size_t)(cl * 16 + lk * 4 + r) * Hn + j * 64 + wu * 16 + l15] = hn;
                }
            }
            if (t < Tn - 1) {
                asm volatile("s_waitcnt vmcnt(0)" ::: "memory");   // same-dword order
                char* eb = hbuf + (size_t)(((cl * 4 + j) * 2 + ((t + 1) & 1)) * 4096);
                const uint32_t tagw = ((uint32_t)(t + 1)) << 16;
#pragma unroll
                for (int r = 0; r < 4; ++r)
                    stdw_l2(eb + (((lk * 4 + r) * 64 + wu * 16 + l15) << 2),
                            (uint32_t)hb[r] | tagw);
            }
        }
        bar_lds();   // B3

        if (ks == 1 && t < Tn - 1) {
#pragma unroll
            for (int r = 0; r < 4; ++r) {
                const int c = j * 128 + (wu >> 1) * 64
                            + ((wu & 1) * 2 + (l15 >> 3)) * 16 + lk * 4 + r;
                *(uint16_t*)((char*)AfrH + swz(c) * 16 + (l15 & 7) * 2) = hb[r];
            }
        }
    }
}

// ===================== TIER 2: R9 flag protocol (proven 1724us) =============
__global__ void pack_w_frag(const float* __restrict__ W, __hip_bfloat16* __restrict__ Wpf,
                            uint32_t* __restrict__ flags) {
    int idx  = blockIdx.x * 256 + threadIdx.x;
    int lane = idx & 63;
    int kb   = (idx >> 6) & 15;
    int nt2  = idx >> 10;
    int g = nt2 & 3, wu = (nt2 >> 2) & 3, jj = nt2 >> 4;
    int row = g * 256 + jj * 64 + wu * 16 + (lane & 15);
    int k0  = kb * 32 + (lane >> 4) * 8;
    const float* src = W + (size_t)row * Kn + k0;
    union { __hip_bfloat16 h[8]; bf16x8 v; } u;
#pragma unroll
    for (int e = 0; e < 8; ++e) u.h[e] = __float2bfloat16(src[e]);
    *(bf16x8*)(Wpf + (size_t)idx * 8) = u.v;
    if (blockIdx.x == 0 && threadIdx.x < 256)
        flags[threadIdx.x] = 0u;
}

__global__ __launch_bounds__(512, 2) void lstm_cluster(
    const float* __restrict__ X, const float* __restrict__ bias,
    const __hip_bfloat16* __restrict__ Wpf, __hip_bfloat16* __restrict__ hbuf,
    uint32_t* __restrict__ flags, float* __restrict__ out)
{
    __shared__ bf16x8 AfrX[2][512];
    __shared__ bf16x8 AfrH[512];
    __shared__ f32x4 Red[4][4][64];
    __shared__ bf16x8 Tp[4][32];

    const int tid = threadIdx.x, lane = tid & 63, w8 = tid >> 6;
    const int wu = w8 & 3, ks = w8 >> 2;
    const int l15 = lane & 15, lk = lane >> 4;
    const int wg = blockIdx.x, cl = wg & 15, j = wg >> 4;

    bf16x8 wf[4][8];
#pragma unroll
    for (int g = 0; g < 4; ++g)
#pragma unroll
        for (int i = 0; i < 8; ++i) {
            const int nt2 = (j * 4 + wu) * 4 + g, kb = ks * 8 + i;
            wf[g][i] = *(const bf16x8*)(Wpf + ((size_t)(nt2 * 16 + kb) * 64 + lane) * 8);
        }
    float bg[4];
#pragma unroll
    for (int g = 0; g < 4; ++g) bg[g] = bias[g * 256 + j * 64 + wu * 16 + l15];
    float c4[4] = {0.f, 0.f, 0.f, 0.f};
    {
        const bf16x8 z = {};
        AfrH[tid] = z;
    }
    const int b = wu * 4 + lk;
    const float* xbase = X + (size_t)(cl * 16 + b) * Tn * In;
    float4 xp[4];
    if (ks == 0) {
#pragma unroll
        for (int cc = 0; cc < 2; ++cc) {
            const int o8 = l15 + cc * 16;
            const float4 v0 = *(const float4*)(xbase + o8 * 8);
            const float4 v1 = *(const float4*)(xbase + o8 * 8 + 4);
            union { __hip_bfloat16 h[8]; bf16x8 v; } u;
            u.h[0] = __float2bfloat16(v0.x); u.h[1] = __float2bfloat16(v0.y);
            u.h[2] = __float2bfloat16(v0.z); u.h[3] = __float2bfloat16(v0.w);
            u.h[4] = __float2bfloat16(v1.x); u.h[5] = __float2bfloat16(v1.y);
            u.h[6] = __float2bfloat16(v1.z); u.h[7] = __float2bfloat16(v1.w);
            AfrX[0][swz(b + 16 * o8)] = u.v;
        }
#pragma unroll
        for (int cc = 0; cc < 2; ++cc) {
            const int o8 = l15 + cc * 16;
            xp[cc * 2]     = *(const float4*)(xbase + In + o8 * 8);
            xp[cc * 2 + 1] = *(const float4*)(xbase + In + o8 * 8 + 4);
        }
    }
    __syncthreads();
#pragma unroll 1
    for (int t = 0; t < Tn; ++t) {
        f32x4 acc[4] = {};
        if (ks == 0) {
            bf16x8 af[8];
#pragma unroll
            for (int i = 0; i < 8; ++i)
                af[i] = AfrX[t & 1][swz(i * 64 + lane)];
#pragma unroll
            for (int i = 0; i < 8; ++i)
#pragma unroll
                for (int g = 0; g < 4; ++g)
                    acc[g] = __builtin_amdgcn_mfma_f32_16x16x32_bf16(af[i], wf[g][i], acc[g], 0, 0, 0);
            if (t + 1 < Tn) {
#pragma unroll
                for (int cc = 0; cc < 2; ++cc) {
                    const int o8 = l15 + cc * 16;
                    union { __hip_bfloat16 h[8]; bf16x8 v; } u;
                    u.h[0] = __float2bfloat16(xp[cc * 2].x); u.h[1] = __float2bfloat16(xp[cc * 2].y);
                    u.h[2] = __float2bfloat16(xp[cc * 2].z); u.h[3] = __float2bfloat16(xp[cc * 2].w);
                    u.h[4] = __float2bfloat16(xp[cc * 2 + 1].x); u.h[5] = __float2bfloat16(xp[cc * 2 + 1].y);
                    u.h[6] = __float2bfloat16(xp[cc * 2 + 1].z); u.h[7] = __float2bfloat16(xp[cc * 2 + 1].w);
                    AfrX[(t + 1) & 1][swz(b + 16 * o8)] = u.v;
                }
            }
        } else if (t > 0 && wu != j) {
            const char* fl = (const char*)flags + (cl * 4 + wu) * 16;
            uint32_t g2 = 0;
            for (;;) {
                u32x4 f = ldflags_llc(fl);
                uint32_t mn = f.x < f.y ? f.x : f.y;
                const uint32_t mn2 = f.z < f.w ? f.z : f.w;
                if (mn2 < mn) mn = mn2;
                if (mn >= (uint32_t)t || ++g2 >= (1u << 12)) break;
            }
            const char* src = (const char*)hbuf + (size_t)((t & 1) * 16 + cl) * 8192
                            + wu * 2048 + lane * 16;
            const bf16x8 r0 = ld16_llc(src);
            const bf16x8 r1 = ld16_llc(src + 1024);
            asm volatile("s_waitcnt vmcnt(0)" ::: "memory");
            __builtin_amdgcn_sched_barrier(0);
            AfrH[swz(wu * 128 + lane)]      = r0;
            AfrH[swz(wu * 128 + lane + 64)] = r1;
        }
        __syncthreads();
        if (ks == 0) {
            if (t + 2 < Tn) {
                const float* xs = xbase + (size_t)(t + 2) * In;
#pragma unroll
                for (int cc = 0; cc < 2; ++cc) {
                    const int o8 = l15 + cc * 16;
                    xp[cc * 2]     = *(const float4*)(xs + o8 * 8);
                    xp[cc * 2 + 1] = *(const float4*)(xs + o8 * 8 + 4);
                }
            }
        } else {
            bf16x8 af[8];
#pragma unroll
            for (int i = 0; i < 8; ++i)
                af[i] = AfrH[swz(i * 64 + lane)];
#pragma unroll
            for (int i = 0; i < 8; ++i)
#pragma unroll
                for (int g = 0; g < 4; ++g)
                    acc[g] = __builtin_amdgcn_mfma_f32_16x16x32_bf16(af[i], wf[g][i], acc[g], 0, 0, 0);
#pragma unroll
            for (int g = 0; g < 4; ++g) Red[wu][g][lane] = acc[g];
        }
        __syncthreads();
        if (ks == 0) {
#pragma unroll
            for (int g = 0; g < 4; ++g) acc[g] += Red[wu][g][lane];
            __hip_bfloat16* tp = (__hip_bfloat16*)&Tp[wu][0];
#pragma unroll
            for (int r = 0; r < 4; ++r) {
                const float pi = acc[0][r] + bg[0];
                const float pj = acc[1][r] + bg[1];
                const float pf = acc[2][r] + bg[2];
                const float po = acc[3][r] + bg[3];
                const float ai = sigmoidf_(pi);
                const float aj = tanhf_(pj);
                const float afv = sigmoidf_(pf);
                const float ao = sigmoidf_(po);
                const float cn = ai * aj + c4[r] * afv;
                c4[r] = cn;
                const float hn = ao * tanhf_(cn);
                if (t < Tn - 1) {
                    const int cp = (lk * 4 + r) * 2 + (l15 >> 3);
                    tp[swz16(cp) * 8 + (l15 & 7)] = __float2bfloat16(hn);
                } else {
                    out[(size_t)(cl * 16 + lk * 4 + r) * Hn + j * 64 + wu * 16 + l15] = hn;
                }
            }
            if (t < Tn - 1) {
                if (lane < 32) {
                    const bf16x8 val = Tp[wu][swz16(lane)];
                    const int clocal = (wu >> 1) * 64 + (lane >> 1)
                                     + 16 * ((wu & 1) * 2 + (lane & 1));
                    AfrH[swz(j * 128 + clocal)] = val;
                    char* dst = (char*)hbuf + (size_t)(((t + 1) & 1) * 16 + cl) * 8192
                              + j * 2048 + clocal * 16;
                    st16_llc(dst, val);
                }
                asm volatile("s_waitcnt vmcnt(0)" ::: "memory");
                if (lane == 0)
                    stdw_llc((char*)flags + (cl * 4 + j) * 16 + wu * 4, (uint32_t)(t + 1));
            }
        }
    }
}

// ===================== TIER 3: R3 fallback ==================================
__global__ void pack_w(const float* __restrict__ W, __hip_bfloat16* __restrict__ Wp) {
    int idx = blockIdx.x * 256 + threadIdx.x;
    int e = idx & 7, l = (idx >> 3) & 63, kb = (idx >> 9) & 15, nt = idx >> 13;
    int n = nt * 16 + (l & 15);
    int k = kb * 32 + (l >> 4) * 8 + e;
    Wp[idx] = __float2bfloat16(W[n * Kn + k]);
}

__global__ __launch_bounds__(1024, 4) void lstm_fused(
    const float* __restrict__ X, const float* __restrict__ bias,
    const __hip_bfloat16* __restrict__ Wp, float* __restrict__ out)
{
    constexpr int LDA = Kn + 8;
    __shared__ __hip_bfloat16 A[16][LDA];
    const int tid = threadIdx.x, wv = tid >> 6, lane = tid & 63;
    const int l15 = lane & 15, lk = lane >> 4, b0 = blockIdx.x * 16;
    const __hip_bfloat16* wp[4];
#pragma unroll
    for (int g = 0; g < 4; ++g) wp[g] = Wp + (size_t)(g * 16 + wv) * (16 * 512) + lane * 8;
    float bslot[4];
#pragma unroll
    for (int g = 0; g < 4; ++g) bslot[g] = bias[g * 256 + wv * 16 + l15];
    float c[4], h[4];
#pragma unroll
    for (int r = 0; r < 4; ++r) { c[r] = 0.f; h[r] = 0.f; }
    const float* xptr = X + ((size_t)(b0 + wv) * Tn) * In + lane * 4;
#pragma unroll 1
    for (int t = 0; t < Tn; ++t) {
        __syncthreads();
        {
            const float4 v = *(const float4*)(xptr + (size_t)t * In);
            __hip_bfloat16 tmp[4];
            tmp[0] = __float2bfloat16(v.x); tmp[1] = __float2bfloat16(v.y);
            tmp[2] = __float2bfloat16(v.z); tmp[3] = __float2bfloat16(v.w);
            *(ushort4*)&A[wv][lane * 4] = *(const ushort4*)tmp;
        }
#pragma unroll
        for (int r = 0; r < 4; ++r)
            A[lk * 4 + r][In + wv * 16 + l15] = __float2bfloat16(h[r]);
        __syncthreads();
        f32x4 acc[4];
#pragma unroll
        for (int g = 0; g < 4; ++g) acc[g] = f32x4{bslot[g], bslot[g], bslot[g], bslot[g]};
        bf16x8 wbuf[2][4];
#pragma unroll
        for (int g = 0; g < 4; ++g) wbuf[0][g] = *(const bf16x8*)(wp[g]);
#pragma unroll
        for (int kb = 0; kb < 16; ++kb) {
            const int cur = kb & 1;
            if (kb < 15) {
#pragma unroll
                for (int g = 0; g < 4; ++g)
                    wbuf[cur ^ 1][g] = *(const bf16x8*)(wp[g] + (kb + 1) * 512);
            }
            const bf16x8 a = *(const bf16x8*)&A[l15][kb * 32 + lk * 8];
#pragma unroll
            for (int g = 0; g < 4; ++g)
                acc[g] = __builtin_amdgcn_mfma_f32_16x16x32_bf16(a, wbuf[cur][g], acc[g], 0, 0, 0);
        }
#pragma unroll
        for (int r = 0; r < 4; ++r) {
            const float ai = sigmoidf_(acc[0][r]);
            const float aj = tanhf_(acc[1][r]);
            const float af = sigmoidf_(acc[2][r]);
            const float ao = sigmoidf_(acc[3][r]);
            const float cn = ai * aj + c[r] * af;
            c[r] = cn;
            h[r] = ao * tanhf_(cn);
            if (t == Tn - 1)
                out[(size_t)(b0 + lk * 4 + r) * Hn + wv * 16 + l15] = h[r];
        }
    }
}

} // namespace

extern "C" void kernel_launch(void* const* d_in, const int* in_sizes, int n_in,
                              void* d_out, int out_size, void* d_ws, size_t ws_size,
                              hipStream_t stream) {
    const float* X    = (const float*)d_in[0];   // [256][512][256] f32
    const float* W    = (const float*)d_in[1];   // [1024][512] f32
    const float* bias = (const float*)d_in[2];   // [1024] f32

    if (ws_size >= (size_t)0x180000) {
        // Tier 1: Wpf @0 (1MB), tagged hbuf @0x100000 (512KB).
        // Assignment tables (2KB) live in d_out -- scratch until t=511 overwrites
        // every word with the final hidden state.
        __hip_bfloat16* Wpf = (__hip_bfloat16*)d_ws;
        char*           hb  = (char*)d_ws + 0x100000;
        uint32_t*       tab = (uint32_t*)d_out;
        pack_w_tag<<<dim3(256), dim3(256), 0, stream>>>(W, Wpf, (unsigned long long*)hb, tab);
        lstm_xcd<<<dim3(256), dim3(512), 0, stream>>>(X, bias, Wpf, hb, tab, (float*)d_out);
    } else if (ws_size >= (size_t)0x142000) {
        // Tier 2 (R9): Wpf @0, hbuf @0x100000 (256KB), flags @0x140000
        __hip_bfloat16* Wpf   = (__hip_bfloat16*)d_ws;
        __hip_bfloat16* hbuf  = (__hip_bfloat16*)((char*)d_ws + 0x100000);
        uint32_t*       flags = (uint32_t*)((char*)d_ws + 0x140000);
        pack_w_frag<<<dim3(256), dim3(256), 0, stream>>>(W, Wpf, flags);
        lstm_cluster<<<dim3(64), dim3(512), 0, stream>>>(X, bias, Wpf, hbuf, flags,
                                                         (float*)d_out);
    } else {
        __hip_bfloat16* Wp = (__hip_bfloat16*)d_ws;
        pack_w<<<dim3(2048), dim3(256), 0, stream>>>(W, Wp);
        lstm_fused<<<dim3(16), dim3(1024), 0, stream>>>(X, bias, Wp, (float*)d_out);
    }
}

// Round 13
// 1118.594 us; speedup vs baseline: 2.0705x; 2.0705x over previous
//
#include <hip/hip_runtime.h>
#include <hip/hip_bf16.h>
#include <stdint.h>

namespace {

constexpr int Tn = 512, In = 256, Hn = 256, Kn = 512;

typedef __attribute__((ext_vector_type(8))) short bf16x8;
typedef __attribute__((ext_vector_type(4))) float f32x4;
typedef __attribute__((ext_vector_type(4))) unsigned int u32x4;

__device__ __forceinline__ float sigmoidf_(float x) { return 1.f / (1.f + __expf(-x)); }
__device__ __forceinline__ float tanhf_(float x)    { return 2.f / (1.f + __expf(-2.f * x)) - 1.f; }

__device__ __forceinline__ int swz(int c) { return c ^ ((c >> 4) & 15); }
__device__ __forceinline__ int swz16(int c) { return c ^ (((c >> 3) & 3) << 1); }

// LDS-only barrier (R11-proven): no vmcnt drain on the critical path
__device__ __forceinline__ void bar_lds() {
    asm volatile("s_waitcnt lgkmcnt(0)\n\ts_barrier" ::: "memory");
}

// sc1 = agent-coherent ops. Store writes THROUGH the local L2 (R12: WRITE_SIZE
// proved L2 residency); load bypasses L1 and probes local L2 before LLC (R12:
// correctness was carried by sc1 iterations). Same-XCD mates -> ~L2 latency.
// sc0 LOADS are L1-pinned (R6/R8/R12 evidence) -- never poll with sc0.
__device__ __forceinline__ void st16_llc(void* p, bf16x8 v) {
    asm volatile("global_store_dwordx4 %0, %1, off sc1" :: "v"(p), "v"(v) : "memory");
}
__device__ __forceinline__ bf16x8 ld16_llc(const void* p) {
    bf16x8 r;
    asm volatile("global_load_dwordx4 %0, %1, off sc1" : "=v"(r) : "v"(p) : "memory");
    return r;
}
__device__ __forceinline__ u32x4 ld16u_llc(const void* p) {
    u32x4 r;
    asm volatile("global_load_dwordx4 %0, %1, off sc1" : "=v"(r) : "v"(p) : "memory");
    return r;
}
__device__ __forceinline__ u32x4 ldflags_llc(const void* p) {
    u32x4 r;
    asm volatile("global_load_dwordx4 %0, %1, off sc1\n\ts_waitcnt vmcnt(0)"
                 : "=v"(r) : "v"(p) : "memory");
    return r;
}
__device__ __forceinline__ void stdw_llc(void* p, uint32_t v) {
    asm volatile("global_store_dword %0, %1, off sc1" :: "v"(p), "v"(v) : "memory");
}
__device__ __forceinline__ uint32_t lddw_llc(const void* p) {
    uint32_t r;
    asm volatile("global_load_dword %0, %1, off sc1\n\ts_waitcnt vmcnt(0)"
                 : "=v"(r) : "v"(p) : "memory");
    return r;
}

// tag check: 8 dwords, hi-u16 must all equal want (wt = want<<16)
__device__ __forceinline__ bool tags8(u32x4 a, u32x4 b, uint32_t wt) {
    uint32_t d = (a.x ^ wt) | (a.y ^ wt) | (a.z ^ wt) | (a.w ^ wt)
               | (b.x ^ wt) | (b.y ^ wt) | (b.z ^ wt) | (b.w ^ wt);
    return (d & 0xFFFF0000u) == 0u;
}
__device__ __forceinline__ bf16x8 pack8(u32x4 a, u32x4 b) {
    union { uint32_t u[4]; bf16x8 v; } r;
    r.u[0] = (a.x & 0xFFFFu) | (a.y << 16);
    r.u[1] = (a.z & 0xFFFFu) | (a.w << 16);
    r.u[2] = (b.x & 0xFFFFu) | (b.y << 16);
    r.u[3] = (b.z & 0xFFFFu) | (b.w << 16);
    return r.v;
}

// ============ TIER 1: XCD-verified clustering + pure-sc1 protocol ===========
// 256 WGs launched; WG0 gathers per-WG XCC_ID, forms 16 clusters x 4 members
// each from a SINGLE XCD; 192 WGs exit. Protocol = R11 tag-in-data, ALL sc1:
// same-XCD mates mean polls hit the shared local L2 instead of the LLC.

__global__ void pack_w_tag(const float* __restrict__ W, __hip_bfloat16* __restrict__ Wpf,
                           unsigned long long* __restrict__ hz, uint32_t* __restrict__ tab) {
    int idx  = blockIdx.x * 256 + threadIdx.x;   // 65536 total
    int lane = idx & 63;
    int kb   = (idx >> 6) & 15;
    int nt2  = idx >> 10;
    int g = nt2 & 3, wu = (nt2 >> 2) & 3, jj = nt2 >> 4;
    int row = g * 256 + jj * 64 + wu * 16 + (lane & 15);
    int k0  = kb * 32 + (lane >> 4) * 8;
    const float* src = W + (size_t)row * Kn + k0;
    union { __hip_bfloat16 h[8]; bf16x8 v; } u;
#pragma unroll
    for (int e = 0; e < 8; ++e) u.h[e] = __float2bfloat16(src[e]);
    *(bf16x8*)(Wpf + (size_t)idx * 8) = u.v;
    // zero tagged hbuf (512KB) every launch (stale tags across graph replays)
    hz[idx] = 0ULL;
    // zero assignment tables (xcdtab[256] + asgn[256], live in d_out scratch)
    if (blockIdx.x == 0 && threadIdx.x < 256) {
        tab[threadIdx.x] = 0u;
        tab[256 + threadIdx.x] = 0u;
    }
}

__global__ __launch_bounds__(512, 2) void lstm_xcd(
    const float* __restrict__ X, const float* __restrict__ bias,
    const __hip_bfloat16* __restrict__ Wpf, char* __restrict__ hbuf,
    uint32_t* __restrict__ tab, float* __restrict__ out)
{
    __shared__ bf16x8 AfrX[2][512];    // 16 KB dbuf x frags (also leader scratch)
    __shared__ bf16x8 AfrH[512];       // 8 KB h frags
    __shared__ f32x4 Red[4][4][64];    // 16 KB x-GEMM partials
    __shared__ uint32_t roleSh;

    const int tid = threadIdx.x, lane = tid & 63, w8 = tid >> 6;
    const int wu = w8 & 3, ks = w8 >> 2;
    const int l15 = lane & 15, lk = lane >> 4;
    const int wg = blockIdx.x;

    uint32_t* xcdtab = tab;
    uint32_t* asgn   = tab + 256;

    // ---- publish own XCD id (verified mechanism: learn_hip m09) ----
    uint32_t xcc;
    asm volatile("s_getreg_b32 %0, hwreg(HW_REG_XCC_ID)" : "=s"(xcc));
    if (tid == 0) {
        uint32_t v = (xcc & 7) + 1;
        asm volatile("global_store_dword %0, %1, off sc1\n\ts_waitcnt vmcnt(0)"
                     :: "v"(xcdtab + wg), "v"(v) : "memory");
    }

    // ---- leader: gather ids, form same-XCD clusters, broadcast roles ----
    if (wg == 0) {
        uint32_t* xtabL = (uint32_t*)&AfrX[0][0];
        uint32_t* asgnL = xtabL + 256;
        if (tid < 256) {
            uint32_t v = 0;
            for (uint32_t g2 = 0; g2 < (1u << 16); ++g2) {
                v = lddw_llc(xcdtab + tid);
                if (v != 0) break;
            }
            xtabL[tid] = v;
            asgnL[tid] = 1u;            // default: EXIT
        }
        __syncthreads();
        if (tid == 0) {
            int cnt[8] = {0, 0, 0, 0, 0, 0, 0, 0};
            int pend[8][4];
            int ncl = 0;
            for (int i = 0; i < 256 && ncl < 16; ++i) {
                const int x = (int)((xtabL[i] - 1u) & 7u);
                pend[x][cnt[x] & 3] = i;
                cnt[x]++;
                if ((cnt[x] & 3) == 0) {        // 4 same-XCD WGs -> one cluster
                    for (int m = 0; m < 4; ++m)
                        asgnL[pend[x][m]] = 2u + (uint32_t)(ncl * 4 + m);
                    ncl++;
                }
            }
        }
        __syncthreads();
        if (tid < 256)
            asm volatile("global_store_dword %0, %1, off sc1"
                         :: "v"(asgn + tid), "v"(asgnL[tid]) : "memory");
        asm volatile("s_waitcnt vmcnt(0)" ::: "memory");
    }

    // ---- fetch own role ----
    if (tid == 0) {
        uint32_t v = 0;
        for (uint32_t g2 = 0; g2 < (1u << 20); ++g2) {
            v = lddw_llc(asgn + wg);
            if (v != 0) break;
        }
        roleSh = v;
    }
    __syncthreads();
    const uint32_t role = roleSh;
    if (role < 2u) return;             // EXIT
    const int slot = (int)(role - 2u);
    const int cl = slot >> 2, j = slot & 3;
    __syncthreads();                   // leader LDS scratch fully retired

    // ---- resident weights: 32 frags / lane (ks picks K-half) ----
    bf16x8 wf[4][8];
#pragma unroll
    for (int g = 0; g < 4; ++g)
#pragma unroll
        for (int i = 0; i < 8; ++i) {
            const int nt2 = (j * 4 + wu) * 4 + g, kb = ks * 8 + i;
            wf[g][i] = *(const bf16x8*)(Wpf + ((size_t)(nt2 * 16 + kb) * 64 + lane) * 8);
        }
    float bg[4];
#pragma unroll
    for (int g = 0; g < 4; ++g) bg[g] = bias[g * 256 + j * 64 + wu * 16 + l15];

    float c4[4] = {0.f, 0.f, 0.f, 0.f};

    {
        const bf16x8 z = {};
        AfrH[tid] = z;
    }

    // ---- prologue: stage x(0); prefetch x(1) ----
    const int b = wu * 4 + lk;
    const float* xbase = X + (size_t)(cl * 16 + b) * Tn * In;
    float4 xp[4];
    if (ks == 0) {
#pragma unroll
        for (int cc = 0; cc < 2; ++cc) {
            const int o8 = l15 + cc * 16;
            const float4 v0 = *(const float4*)(xbase + o8 * 8);
            const float4 v1 = *(const float4*)(xbase + o8 * 8 + 4);
            union { __hip_bfloat16 h[8]; bf16x8 v; } u;
            u.h[0] = __float2bfloat16(v0.x); u.h[1] = __float2bfloat16(v0.y);
            u.h[2] = __float2bfloat16(v0.z); u.h[3] = __float2bfloat16(v0.w);
            u.h[4] = __float2bfloat16(v1.x); u.h[5] = __float2bfloat16(v1.y);
            u.h[6] = __float2bfloat16(v1.z); u.h[7] = __float2bfloat16(v1.w);
            AfrX[0][swz(b + 16 * o8)] = u.v;
        }
#pragma unroll
        for (int cc = 0; cc < 2; ++cc) {
            const int o8 = l15 + cc * 16;
            xp[cc * 2]     = *(const float4*)(xbase + In + o8 * 8);
            xp[cc * 2 + 1] = *(const float4*)(xbase + In + o8 * 8 + 4);
        }
    }
    __syncthreads();

#pragma unroll 1
    for (int t = 0; t < Tn; ++t) {
        if (ks == 0) {
            // ---- x-GEMM(t) -> Red; stage x(t+1) (off critical path) ----
            f32x4 acc[4] = {};
            bf16x8 af[8];
#pragma unroll
            for (int i = 0; i < 8; ++i)
                af[i] = AfrX[t & 1][swz(i * 64 + lane)];
#pragma unroll
            for (int i = 0; i < 8; ++i)
#pragma unroll
                for (int g = 0; g < 4; ++g)
                    acc[g] = __builtin_amdgcn_mfma_f32_16x16x32_bf16(af[i], wf[g][i], acc[g], 0, 0, 0);
#pragma unroll
            for (int g = 0; g < 4; ++g) Red[wu][g][lane] = acc[g];
            if (t + 1 < Tn) {
#pragma unroll
                for (int cc = 0; cc < 2; ++cc) {
                    const int o8 = l15 + cc * 16;
                    union { __hip_bfloat16 h[8]; bf16x8 v; } u;
                    u.h[0] = __float2bfloat16(xp[cc * 2].x); u.h[1] = __float2bfloat16(xp[cc * 2].y);
                    u.h[2] = __float2bfloat16(xp[cc * 2].z); u.h[3] = __float2bfloat16(xp[cc * 2].w);
                    u.h[4] = __float2bfloat16(xp[cc * 2 + 1].x); u.h[5] = __float2bfloat16(xp[cc * 2 + 1].y);
                    u.h[6] = __float2bfloat16(xp[cc * 2 + 1].z); u.h[7] = __float2bfloat16(xp[cc * 2 + 1].w);
                    AfrX[(t + 1) & 1][swz(b + 16 * o8)] = u.v;
                }
            }
        } else if (t > 0 && wu != j) {
            // ---- import mate wu's h(t-1): sc1-only tagged poll (local-L2 hit) ----
            const char* ib = hbuf + (size_t)(((cl * 4 + wu) * 2 + (t & 1)) * 4096)
                           + (lane & 15) * 256 + (lane >> 4) * 32;
            const uint32_t wt = ((uint32_t)t) << 16;
            u32x4 A0 = {}, A1 = {}, B0 = {}, B1 = {};
            bool f0 = false, f1 = false;
            int g2 = 0;
            for (;;) {
                if (!f0) { A0 = ld16u_llc(ib);       A1 = ld16u_llc(ib + 16); }
                if (!f1) { B0 = ld16u_llc(ib + 128); B1 = ld16u_llc(ib + 144); }
                asm volatile("s_waitcnt vmcnt(0)" ::: "memory");
                f0 = f0 || tags8(A0, A1, wt);
                f1 = f1 || tags8(B0, B1, wt);
                if (__all(f0 && f1) || ++g2 >= 4096) break;
            }
            __builtin_amdgcn_sched_barrier(0);
            AfrH[swz(wu * 128 + lane)]      = pack8(A0, A1);
            AfrH[swz(wu * 128 + 64 + lane)] = pack8(B0, B1);
        }
        bar_lds();   // B2: AfrH(t-1) complete, Red(t) complete, AfrX(t+1) staged

        uint16_t hb[4];
        if (ks == 0) {
            if (t + 2 < Tn) {
                const float* xs = xbase + (size_t)(t + 2) * In;
#pragma unroll
                for (int cc = 0; cc < 2; ++cc) {
                    const int o8 = l15 + cc * 16;
                    xp[cc * 2]     = *(const float4*)(xs + o8 * 8);
                    xp[cc * 2 + 1] = *(const float4*)(xs + o8 * 8 + 4);
                }
            }
        } else {
            // ---- h-GEMM + reduce + gates + export (single wave, R11-proven) ----
            f32x4 acc[4] = {};
            bf16x8 af[8];
#pragma unroll
            for (int i = 0; i < 8; ++i)
                af[i] = AfrH[swz(i * 64 + lane)];
#pragma unroll
            for (int i = 0; i < 8; ++i)
#pragma unroll
                for (int g = 0; g < 4; ++g)
                    acc[g] = __builtin_amdgcn_mfma_f32_16x16x32_bf16(af[i], wf[g][i], acc[g], 0, 0, 0);
#pragma unroll
            for (int g = 0; g < 4; ++g) acc[g] += Red[wu][g][lane];
#pragma unroll
            for (int r = 0; r < 4; ++r) {
                const float pi = acc[0][r] + bg[0];
                const float pj = acc[1][r] + bg[1];
                const float pf = acc[2][r] + bg[2];
                const float po = acc[3][r] + bg[3];
                const float ai = sigmoidf_(pi);
                const float aj = tanhf_(pj);
                const float afv = sigmoidf_(pf);
                const float ao = sigmoidf_(po);
                const float cn = ai * aj + c4[r] * afv;
                c4[r] = cn;
                const float hn = ao * tanhf_(cn);
                if (t < Tn - 1) {
                    union { __hip_bfloat16 bh; uint16_t u; } cv;
                    cv.bh = __float2bfloat16(hn);
                    hb[r] = cv.u;
                } else {
                    out[(size_t)(cl * 16 + lk * 4 + r) * Hn + j * 64 + wu * 16 + l15] = hn;
                }
            }
            if (t < Tn - 1) {
                asm volatile("s_waitcnt vmcnt(0)" ::: "memory");   // same-dword order
                char* eb = hbuf + (size_t)(((cl * 4 + j) * 2 + ((t + 1) & 1)) * 4096);
                const uint32_t tagw = ((uint32_t)(t + 1)) << 16;
#pragma unroll
                for (int r = 0; r < 4; ++r)
                    stdw_llc(eb + (((lk * 4 + r) * 64 + wu * 16 + l15) << 2),
                             (uint32_t)hb[r] | tagw);
            }
        }
        bar_lds();   // B3

        if (ks == 1 && t < Tn - 1) {
#pragma unroll
            for (int r = 0; r < 4; ++r) {
                const int c = j * 128 + (wu >> 1) * 64
                            + ((wu & 1) * 2 + (l15 >> 3)) * 16 + lk * 4 + r;
                *(uint16_t*)((char*)AfrH + swz(c) * 16 + (l15 & 7) * 2) = hb[r];
            }
        }
    }
}

// ===================== TIER 2: R9 flag protocol (proven 1724us) =============
__global__ void pack_w_frag(const float* __restrict__ W, __hip_bfloat16* __restrict__ Wpf,
                            uint32_t* __restrict__ flags) {
    int idx  = blockIdx.x * 256 + threadIdx.x;
    int lane = idx & 63;
    int kb   = (idx >> 6) & 15;
    int nt2  = idx >> 10;
    int g = nt2 & 3, wu = (nt2 >> 2) & 3, jj = nt2 >> 4;
    int row = g * 256 + jj * 64 + wu * 16 + (lane & 15);
    int k0  = kb * 32 + (lane >> 4) * 8;
    const float* src = W + (size_t)row * Kn + k0;
    union { __hip_bfloat16 h[8]; bf16x8 v; } u;
#pragma unroll
    for (int e = 0; e < 8; ++e) u.h[e] = __float2bfloat16(src[e]);
    *(bf16x8*)(Wpf + (size_t)idx * 8) = u.v;
    if (blockIdx.x == 0 && threadIdx.x < 256)
        flags[threadIdx.x] = 0u;
}

__global__ __launch_bounds__(512, 2) void lstm_cluster(
    const float* __restrict__ X, const float* __restrict__ bias,
    const __hip_bfloat16* __restrict__ Wpf, __hip_bfloat16* __restrict__ hbuf,
    uint32_t* __restrict__ flags, float* __restrict__ out)
{
    __shared__ bf16x8 AfrX[2][512];
    __shared__ bf16x8 AfrH[512];
    __shared__ f32x4 Red[4][4][64];
    __shared__ bf16x8 Tp[4][32];

    const int tid = threadIdx.x, lane = tid & 63, w8 = tid >> 6;
    const int wu = w8 & 3, ks = w8 >> 2;
    const int l15 = lane & 15, lk = lane >> 4;
    const int wg = blockIdx.x, cl = wg & 15, j = wg >> 4;

    bf16x8 wf[4][8];
#pragma unroll
    for (int g = 0; g < 4; ++g)
#pragma unroll
        for (int i = 0; i < 8; ++i) {
            const int nt2 = (j * 4 + wu) * 4 + g, kb = ks * 8 + i;
            wf[g][i] = *(const bf16x8*)(Wpf + ((size_t)(nt2 * 16 + kb) * 64 + lane) * 8);
        }
    float bg[4];
#pragma unroll
    for (int g = 0; g < 4; ++g) bg[g] = bias[g * 256 + j * 64 + wu * 16 + l15];
    float c4[4] = {0.f, 0.f, 0.f, 0.f};
    {
        const bf16x8 z = {};
        AfrH[tid] = z;
    }
    const int b = wu * 4 + lk;
    const float* xbase = X + (size_t)(cl * 16 + b) * Tn * In;
    float4 xp[4];
    if (ks == 0) {
#pragma unroll
        for (int cc = 0; cc < 2; ++cc) {
            const int o8 = l15 + cc * 16;
            const float4 v0 = *(const float4*)(xbase + o8 * 8);
            const float4 v1 = *(const float4*)(xbase + o8 * 8 + 4);
            union { __hip_bfloat16 h[8]; bf16x8 v; } u;
            u.h[0] = __float2bfloat16(v0.x); u.h[1] = __float2bfloat16(v0.y);
            u.h[2] = __float2bfloat16(v0.z); u.h[3] = __float2bfloat16(v0.w);
            u.h[4] = __float2bfloat16(v1.x); u.h[5] = __float2bfloat16(v1.y);
            u.h[6] = __float2bfloat16(v1.z); u.h[7] = __float2bfloat16(v1.w);
            AfrX[0][swz(b + 16 * o8)] = u.v;
        }
#pragma unroll
        for (int cc = 0; cc < 2; ++cc) {
            const int o8 = l15 + cc * 16;
            xp[cc * 2]     = *(const float4*)(xbase + In + o8 * 8);
            xp[cc * 2 + 1] = *(const float4*)(xbase + In + o8 * 8 + 4);
        }
    }
    __syncthreads();
#pragma unroll 1
    for (int t = 0; t < Tn; ++t) {
        f32x4 acc[4] = {};
        if (ks == 0) {
            bf16x8 af[8];
#pragma unroll
            for (int i = 0; i < 8; ++i)
                af[i] = AfrX[t & 1][swz(i * 64 + lane)];
#pragma unroll
            for (int i = 0; i < 8; ++i)
#pragma unroll
                for (int g = 0; g < 4; ++g)
                    acc[g] = __builtin_amdgcn_mfma_f32_16x16x32_bf16(af[i], wf[g][i], acc[g], 0, 0, 0);
            if (t + 1 < Tn) {
#pragma unroll
                for (int cc = 0; cc < 2; ++cc) {
                    const int o8 = l15 + cc * 16;
                    union { __hip_bfloat16 h[8]; bf16x8 v; } u;
                    u.h[0] = __float2bfloat16(xp[cc * 2].x); u.h[1] = __float2bfloat16(xp[cc * 2].y);
                    u.h[2] = __float2bfloat16(xp[cc * 2].z); u.h[3] = __float2bfloat16(xp[cc * 2].w);
                    u.h[4] = __float2bfloat16(xp[cc * 2 + 1].x); u.h[5] = __float2bfloat16(xp[cc * 2 + 1].y);
                    u.h[6] = __float2bfloat16(xp[cc * 2 + 1].z); u.h[7] = __float2bfloat16(xp[cc * 2 + 1].w);
                    AfrX[(t + 1) & 1][swz(b + 16 * o8)] = u.v;
                }
            }
        } else if (t > 0 && wu != j) {
            const char* fl = (const char*)flags + (cl * 4 + wu) * 16;
            uint32_t g2 = 0;
            for (;;) {
                u32x4 f = ldflags_llc(fl);
                uint32_t mn = f.x < f.y ? f.x : f.y;
                const uint32_t mn2 = f.z < f.w ? f.z : f.w;
                if (mn2 < mn) mn = mn2;
                if (mn >= (uint32_t)t || ++g2 >= (1u << 12)) break;
            }
            const char* src = (const char*)hbuf + (size_t)((t & 1) * 16 + cl) * 8192
                            + wu * 2048 + lane * 16;
            const bf16x8 r0 = ld16_llc(src);
            const bf16x8 r1 = ld16_llc(src + 1024);
            asm volatile("s_waitcnt vmcnt(0)" ::: "memory");
            __builtin_amdgcn_sched_barrier(0);
            AfrH[swz(wu * 128 + lane)]      = r0;
            AfrH[swz(wu * 128 + lane + 64)] = r1;
        }
        __syncthreads();
        if (ks == 0) {
            if (t + 2 < Tn) {
                const float* xs = xbase + (size_t)(t + 2) * In;
#pragma unroll
                for (int cc = 0; cc < 2; ++cc) {
                    const int o8 = l15 + cc * 16;
                    xp[cc * 2]     = *(const float4*)(xs + o8 * 8);
                    xp[cc * 2 + 1] = *(const float4*)(xs + o8 * 8 + 4);
                }
            }
        } else {
            bf16x8 af[8];
#pragma unroll
            for (int i = 0; i < 8; ++i)
                af[i] = AfrH[swz(i * 64 + lane)];
#pragma unroll
            for (int i = 0; i < 8; ++i)
#pragma unroll
                for (int g = 0; g < 4; ++g)
                    acc[g] = __builtin_amdgcn_mfma_f32_16x16x32_bf16(af[i], wf[g][i], acc[g], 0, 0, 0);
#pragma unroll
            for (int g = 0; g < 4; ++g) Red[wu][g][lane] = acc[g];
        }
        __syncthreads();
        if (ks == 0) {
#pragma unroll
            for (int g = 0; g < 4; ++g) acc[g] += Red[wu][g][lane];
            __hip_bfloat16* tp = (__hip_bfloat16*)&Tp[wu][0];
#pragma unroll
            for (int r = 0; r < 4; ++r) {
                const float pi = acc[0][r] + bg[0];
                const float pj = acc[1][r] + bg[1];
                const float pf = acc[2][r] + bg[2];
                const float po = acc[3][r] + bg[3];
                const float ai = sigmoidf_(pi);
                const float aj = tanhf_(pj);
                const float afv = sigmoidf_(pf);
                const float ao = sigmoidf_(po);
                const float cn = ai * aj + c4[r] * afv;
                c4[r] = cn;
                const float hn = ao * tanhf_(cn);
                if (t < Tn - 1) {
                    const int cp = (lk * 4 + r) * 2 + (l15 >> 3);
                    tp[swz16(cp) * 8 + (l15 & 7)] = __float2bfloat16(hn);
                } else {
                    out[(size_t)(cl * 16 + lk * 4 + r) * Hn + j * 64 + wu * 16 + l15] = hn;
                }
            }
            if (t < Tn - 1) {
                if (lane < 32) {
                    const bf16x8 val = Tp[wu][swz16(lane)];
                    const int clocal = (wu >> 1) * 64 + (lane >> 1)
                                     + 16 * ((wu & 1) * 2 + (lane & 1));
                    AfrH[swz(j * 128 + clocal)] = val;
                    char* dst = (char*)hbuf + (size_t)(((t + 1) & 1) * 16 + cl) * 8192
                              + j * 2048 + clocal * 16;
                    st16_llc(dst, val);
                }
                asm volatile("s_waitcnt vmcnt(0)" ::: "memory");
                if (lane == 0)
                    stdw_llc((char*)flags + (cl * 4 + j) * 16 + wu * 4, (uint32_t)(t + 1));
            }
        }
    }
}

// ===================== TIER 3: R3 fallback ==================================
__global__ void pack_w(const float* __restrict__ W, __hip_bfloat16* __restrict__ Wp) {
    int idx = blockIdx.x * 256 + threadIdx.x;
    int e = idx & 7, l = (idx >> 3) & 63, kb = (idx >> 9) & 15, nt = idx >> 13;
    int n = nt * 16 + (l & 15);
    int k = kb * 32 + (l >> 4) * 8 + e;
    Wp[idx] = __float2bfloat16(W[n * Kn + k]);
}

__global__ __launch_bounds__(1024, 4) void lstm_fused(
    const float* __restrict__ X, const float* __restrict__ bias,
    const __hip_bfloat16* __restrict__ Wp, float* __restrict__ out)
{
    constexpr int LDA = Kn + 8;
    __shared__ __hip_bfloat16 A[16][LDA];
    const int tid = threadIdx.x, wv = tid >> 6, lane = tid & 63;
    const int l15 = lane & 15, lk = lane >> 4, b0 = blockIdx.x * 16;
    const __hip_bfloat16* wp[4];
#pragma unroll
    for (int g = 0; g < 4; ++g) wp[g] = Wp + (size_t)(g * 16 + wv) * (16 * 512) + lane * 8;
    float bslot[4];
#pragma unroll
    for (int g = 0; g < 4; ++g) bslot[g] = bias[g * 256 + wv * 16 + l15];
    float c[4], h[4];
#pragma unroll
    for (int r = 0; r < 4; ++r) { c[r] = 0.f; h[r] = 0.f; }
    const float* xptr = X + ((size_t)(b0 + wv) * Tn) * In + lane * 4;
#pragma unroll 1
    for (int t = 0; t < Tn; ++t) {
        __syncthreads();
        {
            const float4 v = *(const float4*)(xptr + (size_t)t * In);
            __hip_bfloat16 tmp[4];
            tmp[0] = __float2bfloat16(v.x); tmp[1] = __float2bfloat16(v.y);
            tmp[2] = __float2bfloat16(v.z); tmp[3] = __float2bfloat16(v.w);
            *(ushort4*)&A[wv][lane * 4] = *(const ushort4*)tmp;
        }
#pragma unroll
        for (int r = 0; r < 4; ++r)
            A[lk * 4 + r][In + wv * 16 + l15] = __float2bfloat16(h[r]);
        __syncthreads();
        f32x4 acc[4];
#pragma unroll
        for (int g = 0; g < 4; ++g) acc[g] = f32x4{bslot[g], bslot[g], bslot[g], bslot[g]};
        bf16x8 wbuf[2][4];
#pragma unroll
        for (int g = 0; g < 4; ++g) wbuf[0][g] = *(const bf16x8*)(wp[g]);
#pragma unroll
        for (int kb = 0; kb < 16; ++kb) {
            const int cur = kb & 1;
            if (kb < 15) {
#pragma unroll
                for (int g = 0; g < 4; ++g)
                    wbuf[cur ^ 1][g] = *(const bf16x8*)(wp[g] + (kb + 1) * 512);
            }
            const bf16x8 a = *(const bf16x8*)&A[l15][kb * 32 + lk * 8];
#pragma unroll
            for (int g = 0; g < 4; ++g)
                acc[g] = __builtin_amdgcn_mfma_f32_16x16x32_bf16(a, wbuf[cur][g], acc[g], 0, 0, 0);
        }
#pragma unroll
        for (int r = 0; r < 4; ++r) {
            const float ai = sigmoidf_(acc[0][r]);
            const float aj = tanhf_(acc[1][r]);
            const float af = sigmoidf_(acc[2][r]);
            const float ao = sigmoidf_(acc[3][r]);
            const float cn = ai * aj + c[r] * af;
            c[r] = cn;
            h[r] = ao * tanhf_(cn);
            if (t == Tn - 1)
                out[(size_t)(b0 + lk * 4 + r) * Hn + wv * 16 + l15] = h[r];
        }
    }
}

} // namespace

extern "C" void kernel_launch(void* const* d_in, const int* in_sizes, int n_in,
                              void* d_out, int out_size, void* d_ws, size_t ws_size,
                              hipStream_t stream) {
    const float* X    = (const float*)d_in[0];   // [256][512][256] f32
    const float* W    = (const float*)d_in[1];   // [1024][512] f32
    const float* bias = (const float*)d_in[2];   // [1024] f32

    if (ws_size >= (size_t)0x180000) {
        // Tier 1: Wpf @0 (1MB), tagged hbuf @0x100000 (512KB).
        // Assignment tables (2KB) live in d_out -- scratch until t=511 overwrites
        // every word with the final hidden state.
        __hip_bfloat16* Wpf = (__hip_bfloat16*)d_ws;
        char*           hb  = (char*)d_ws + 0x100000;
        uint32_t*       tab = (uint32_t*)d_out;
        pack_w_tag<<<dim3(256), dim3(256), 0, stream>>>(W, Wpf, (unsigned long long*)hb, tab);
        lstm_xcd<<<dim3(256), dim3(512), 0, stream>>>(X, bias, Wpf, hb, tab, (float*)d_out);
    } else if (ws_size >= (size_t)0x142000) {
        // Tier 2 (R9): Wpf @0, hbuf @0x100000 (256KB), flags @0x140000
        __hip_bfloat16* Wpf   = (__hip_bfloat16*)d_ws;
        __hip_bfloat16* hbuf  = (__hip_bfloat16*)((char*)d_ws + 0x100000);
        uint32_t*       flags = (uint32_t*)((char*)d_ws + 0x140000);
        pack_w_frag<<<dim3(256), dim3(256), 0, stream>>>(W, Wpf, flags);
        lstm_cluster<<<dim3(64), dim3(512), 0, stream>>>(X, bias, Wpf, hbuf, flags,
                                                         (float*)d_out);
    } else {
        __hip_bfloat16* Wp = (__hip_bfloat16*)d_ws;
        pack_w<<<dim3(2048), dim3(256), 0, stream>>>(W, Wp);
        lstm_fused<<<dim3(16), dim3(1024), 0, stream>>>(X, bias, Wp, (float*)d_out);
    }
}